// Round 6
// baseline (333.124 us; speedup 1.0000x reference)
//
#include <hip/hip_runtime.h>
#include <stdint.h>

typedef _Float16 f16;
typedef f16 f16x8 __attribute__((ext_vector_type(8)));
typedef float f32x4 __attribute__((ext_vector_type(4)));

#define MFMA(a,b,c) __builtin_amdgcn_mfma_f32_16x16x32_f16(a, b, c, 0, 0, 0)

__device__ __forceinline__ float sigmoidf_(float z) { return 1.0f / (1.0f + __expf(-z)); }

// ---------------------------------------------------------------------------
// prep: scale[b]; weights -> f16; zero out[0..63].
// Wopt: fragment-permuted [Aq;Ak;Av] (192x2048):
//   (r,k) -> ((rt*64+kc)*16+(r&15))*32 + ((k>>3)&3)*8 + (k&7), rt=r>>4, kc=k>>5
// Wsm = 9 x (64x64): Aq1,Ak1,Av1,Aq5,Ak5,Av5,Ao,Ao1,Ao5
// ---------------------------------------------------------------------------
__global__ void prep_kernel(const float* __restrict__ L,
    const float* __restrict__ Aq, const float* __restrict__ Ak, const float* __restrict__ Av,
    const float* __restrict__ Aq1, const float* __restrict__ Ak1, const float* __restrict__ Av1,
    const float* __restrict__ Aq5, const float* __restrict__ Ak5, const float* __restrict__ Av5,
    const float* __restrict__ Ao, const float* __restrict__ Ao1, const float* __restrict__ Ao5,
    float* __restrict__ scale, f16* __restrict__ Wopt, f16* __restrict__ Wsm,
    float* __restrict__ out)
{
  __shared__ float r4[4];
  int blk = blockIdx.x, t = threadIdx.x;
  if (blk < 64) {
    float v = (L[blk * 512 + t] >= 1.0f) ? 1.0f : 0.0f;
    #pragma unroll
    for (int off = 32; off; off >>= 1) v += __shfl_down(v, off);
    if ((t & 63) == 0) r4[t >> 6] = v;
    __syncthreads();
    if (t == 0) scale[blk] = sqrtf(r4[0] + r4[1] + r4[2] + r4[3] + 1.0f);
  } else if (blk < 160) {
    int base = (blk - 64) * 4096;
    for (int i = 0; i < 16; i++) {
      int idx = base + t + i * 256;
      int r = idx >> 11, k = idx & 2047;
      float v = (r < 64) ? Aq[r * 2048 + k]
              : (r < 128) ? Ak[(r - 64) * 2048 + k]
              : Av[(r - 128) * 2048 + k];
      int rt = r >> 4, lr = r & 15, kc = k >> 5, qq = (k >> 3) & 3, jj = k & 7;
      Wopt[((rt * 64 + kc) * 16 + lr) * 32 + qq * 8 + jj] = (f16)v;
    }
  } else if (blk < 169) {
    int j = blk - 160;
    const float* s = (j == 0) ? Aq1 : (j == 1) ? Ak1 : (j == 2) ? Av1 : (j == 3) ? Aq5
                   : (j == 4) ? Ak5 : (j == 5) ? Av5 : (j == 6) ? Ao : (j == 7) ? Ao1 : Ao5;
    for (int i = 0; i < 16; i++) { int idx = t + i * 256; Wsm[j * 4096 + idx] = (f16)s[idx]; }
  } else {
    if (t < 64) out[t] = 0.0f;
  }
}

// ---------------------------------------------------------------------------
// xt: pure streaming transpose+convert x[b][f][n] fp32 -> xT[b][n][f] f16.
// grid (32 f-tiles, 64 b), 256 thr, LDS [256][68] f16 (stride 68 -> bank
// stride 2 -> 2-way conflicts = free). Coalesced reads and 128B-row writes.
// ---------------------------------------------------------------------------
__global__ __launch_bounds__(256) void xt_kernel(const float* __restrict__ x,
                                                 f16* __restrict__ xT)
{
  int ft = blockIdx.x, b = blockIdx.y;
  int t = threadIdx.x;
  __shared__ f16 T[256 * 68];
  int f0 = ft * 64;
  int cl = t & 63, fg = t >> 6;  // fg 0..3
  const float* xb = x + (size_t)b * 524288 + (size_t)f0 * 256;
  #pragma unroll
  for (int i = 0; i < 16; i++) {
    int fl = i * 4 + fg;
    #pragma unroll
    for (int j = 0; j < 4; j++) {
      float v = xb[(size_t)fl * 256 + cl + j * 64];
      T[(cl + j * 64) * 68 + fl] = (f16)v;
    }
  }
  __syncthreads();
  f16* ob = xT + (size_t)b * 524288 + (size_t)t * 2048 + f0;
  #pragma unroll
  for (int k = 0; k < 8; k++)
    *(uint4*)(ob + k * 8) = *(const uint4*)&T[t * 68 + k * 8];
}

// ---------------------------------------------------------------------------
// qkv: zero-LDS zero-barrier streaming MFMA GEMM from k-contiguous xT.
// Block (g=32-token group, b); wave w owns r-tiles w*3..w*3+2.
// Out[n][r]=sigmoid(sum_f xT[n][f] Wcat[r][f]): Q[n][r], K[n][r], V[r][n].
// ---------------------------------------------------------------------------
__global__ __launch_bounds__(256) void qkv_kernel(const f16* __restrict__ xT,
    const f16* __restrict__ Wopt, f16* __restrict__ Qt, f16* __restrict__ Kt,
    f16* __restrict__ Vg)
{
  int b = blockIdx.y, n0 = blockIdx.x * 32;
  int t = threadIdx.x, lane = t & 63, w = t >> 6;
  int l15 = lane & 15, q = lane >> 4;
  f32x4 acc[2][3] = {};
  const f16* a0p = xT + (size_t)b * 524288 + (size_t)(n0 + l15) * 2048 + q * 8;
  const f16* a1p = a0p + 16 * 2048;
  const f16* wb = Wopt + ((size_t)(w * 3) * 1024 + l15) * 32 + q * 8;

  #pragma unroll 4
  for (int kc = 0; kc < 64; kc++) {
    f16x8 af0 = *(const f16x8*)(a0p + kc * 32);
    f16x8 af1 = *(const f16x8*)(a1p + kc * 32);
    #pragma unroll
    for (int j = 0; j < 3; j++) {
      f16x8 bf = *(const f16x8*)(wb + (size_t)(j * 64 + kc) * 512);
      acc[0][j] = MFMA(af0, bf, acc[0][j]);
      acc[1][j] = MFMA(af1, bf, acc[1][j]);
    }
  }

  #pragma unroll
  for (int nt = 0; nt < 2; nt++)
    #pragma unroll
    for (int j = 0; j < 3; j++) {
      int rr = (w * 3 + j) * 16 + l15;
      float s[4];
      #pragma unroll
      for (int reg = 0; reg < 4; reg++) s[reg] = sigmoidf_(acc[nt][j][reg]);
      int nbase = n0 + nt * 16 + q * 4;
      if (rr < 64) {
        #pragma unroll
        for (int reg = 0; reg < 4; reg++)
          Qt[(size_t)b * 16384 + (size_t)(nbase + reg) * 64 + rr] = (f16)s[reg];
      } else if (rr < 128) {
        #pragma unroll
        for (int reg = 0; reg < 4; reg++)
          Kt[(size_t)b * 16384 + (size_t)(nbase + reg) * 64 + (rr - 64)] = (f16)s[reg];
      } else {
        union { f16 h[4]; uint2 u; } pk;
        #pragma unroll
        for (int reg = 0; reg < 4; reg++) pk.h[reg] = (f16)s[reg];
        *(uint2*)(Vg + (size_t)b * 16384 + (size_t)(rr - 128) * 256 + nbase) = pk.u;
      }
    }
}

// ---------------------------------------------------------------------------
// proj<L>: layer-L (1 or 2) Q/K/V projection from M[b][m][s] (k=s contig).
// Zero LDS, zero barriers. Block (g=64-token group, b), wave w -> r-tile w
// of each of Q,K,V.
// ---------------------------------------------------------------------------
template<int LAYER>
__global__ __launch_bounds__(256) void proj_kernel(const f16* __restrict__ M,
    const f16* __restrict__ Wsm, f16* __restrict__ Qt, f16* __restrict__ Kt,
    f16* __restrict__ Vg)
{
  int b = blockIdx.y, n0 = blockIdx.x * 64;
  int t = threadIdx.x, lane = t & 63, w = t >> 6;
  int l15 = lane & 15, q = lane >> 4;
  const f16* Wq = Wsm + (size_t)(LAYER == 1 ? 0 : 3) * 4096;
  const f16* Wk = Wq + 4096;
  const f16* Wv = Wq + 8192;
  int r = w * 16 + l15;
  f16x8 bq0 = *(const f16x8*)(Wq + r * 64 + q * 8);
  f16x8 bq1 = *(const f16x8*)(Wq + r * 64 + 32 + q * 8);
  f16x8 bk0 = *(const f16x8*)(Wk + r * 64 + q * 8);
  f16x8 bk1 = *(const f16x8*)(Wk + r * 64 + 32 + q * 8);
  f16x8 bv0 = *(const f16x8*)(Wv + r * 64 + q * 8);
  f16x8 bv1 = *(const f16x8*)(Wv + r * 64 + 32 + q * 8);
  const f16* mb = M + (size_t)b * 16384 + (size_t)(n0 + l15) * 64 + q * 8;

  f32x4 aq[4] = {}, ak[4] = {}, av[4] = {};
  #pragma unroll
  for (int nt = 0; nt < 4; nt++) {
    f16x8 a0 = *(const f16x8*)(mb + nt * 1024);
    f16x8 a1 = *(const f16x8*)(mb + nt * 1024 + 32);
    aq[nt] = MFMA(a0, bq0, aq[nt]); aq[nt] = MFMA(a1, bq1, aq[nt]);
    ak[nt] = MFMA(a0, bk0, ak[nt]); ak[nt] = MFMA(a1, bk1, ak[nt]);
    av[nt] = MFMA(a0, bv0, av[nt]); av[nt] = MFMA(a1, bv1, av[nt]);
  }
  #pragma unroll
  for (int nt = 0; nt < 4; nt++) {
    int nbase = n0 + nt * 16 + q * 4;
    #pragma unroll
    for (int reg = 0; reg < 4; reg++) {
      Qt[(size_t)b * 16384 + (size_t)(nbase + reg) * 64 + r] = (f16)sigmoidf_(aq[nt][reg]);
      Kt[(size_t)b * 16384 + (size_t)(nbase + reg) * 64 + r] = (f16)sigmoidf_(ak[nt][reg]);
    }
    union { f16 h[4]; uint2 u; } pk;
    #pragma unroll
    for (int reg = 0; reg < 4; reg++) pk.h[reg] = (f16)sigmoidf_(av[nt][reg]);
    *(uint2*)(Vg + (size_t)b * 16384 + (size_t)r * 256 + nbase) = pk.u;
  }
}

// ---------------------------------------------------------------------------
// attn<L>: attention block for layer L. grid (4,64), 512 thr, ~126 KB LDS.
// Stages Q-slice/K/V from global, computes S=exp(QK^T*sinv), denom, AV,
// normalize, O-proj (Wo_L), silu -> M' (L<2) or final reduction (L==2).
// ---------------------------------------------------------------------------
template<int LAYER>
__global__ __launch_bounds__(512) void attn_kernel(const float* __restrict__ x,
    const float* __restrict__ scale, const f16* __restrict__ Wsm,
    const f16* __restrict__ Qtg, const f16* __restrict__ Ktg, const f16* __restrict__ Vgg,
    f16* __restrict__ Mout, float* __restrict__ out)
{
  int g = blockIdx.x, b = blockIdx.y, n0 = g * 64;
  int t = threadIdx.x, lane = t & 63, w = t >> 6;
  int l15 = lane & 15, q = lane >> 4;
  __shared__ f16 KT[256 * 72];
  __shared__ f16 SM[64 * 264];
  __shared__ f16 VM[64 * 264];
  __shared__ f16 QT[64 * 72];
  __shared__ f16 OT[64 * 72];
  __shared__ float denomS[64];

  float sinv = 1.0f / scale[b];
  if (t < 64) denomS[t] = 0.0f;

  const f16* Wo = Wsm + (size_t)(LAYER == 0 ? 6 : (LAYER == 1 ? 7 : 8)) * 4096;

  // stage
  {
    const uint4* qs = (const uint4*)(Qtg + (size_t)b * 16384 + (size_t)n0 * 64);
    { int n = t >> 3, c = t & 7; *(uint4*)&QT[n * 72 + c * 8] = qs[t]; }
    const uint4* ks = (const uint4*)(Ktg + (size_t)b * 16384);
    const uint4* vs = (const uint4*)(Vgg + (size_t)b * 16384);
    #pragma unroll
    for (int i = 0; i < 4; i++) {
      int id = t + i * 512;
      int m = id >> 3, c = id & 7;
      *(uint4*)&KT[m * 72 + c * 8] = ks[id];
      int r = id >> 5, c2 = id & 31;
      *(uint4*)&VM[r * 264 + c2 * 8] = vs[id];
    }
  }
  __syncthreads();

  // S = exp(QK^T * sinv) -> SM [64][264]; denom via shfl + LDS atomic
  {
    int nt = w >> 1;
    f16x8 a0 = *(const f16x8*)&QT[(nt * 16 + l15) * 72 + q * 8];
    f16x8 a1 = *(const f16x8*)&QT[(nt * 16 + l15) * 72 + 32 + q * 8];
    float dsum[4] = {0.f, 0.f, 0.f, 0.f};
    #pragma unroll
    for (int mi = 0; mi < 8; mi++) {
      int mt = (w & 1) * 8 + mi;
      f16x8 b0 = *(const f16x8*)&KT[(mt * 16 + l15) * 72 + q * 8];
      f16x8 b1 = *(const f16x8*)&KT[(mt * 16 + l15) * 72 + 32 + q * 8];
      f32x4 acc = {}; acc = MFMA(a0, b0, acc); acc = MFMA(a1, b1, acc);
      #pragma unroll
      for (int reg = 0; reg < 4; reg++) {
        float e = __expf(acc[reg] * sinv);
        dsum[reg] += e;
        SM[(nt * 16 + q * 4 + reg) * 264 + mt * 16 + l15] = (f16)e;
      }
    }
    #pragma unroll
    for (int reg = 0; reg < 4; reg++) {
      #pragma unroll
      for (int mask = 1; mask < 16; mask <<= 1) dsum[reg] += __shfl_xor(dsum[reg], mask);
    }
    if (l15 == 0) {
      #pragma unroll
      for (int reg = 0; reg < 4; reg++) atomicAdd(&denomS[nt * 16 + q * 4 + reg], dsum[reg]);
    }
  }
  __syncthreads();

  // AV: o^T[n][r] = sum_m S[n][m] VM[r][m]; normalize -> OT
  {
    int nt = w >> 1;
    f32x4 oacc[2] = {};
    #pragma unroll
    for (int kc = 0; kc < 8; kc++) {
      f16x8 af = *(const f16x8*)&SM[(nt * 16 + l15) * 264 + kc * 32 + q * 8];
      #pragma unroll
      for (int j = 0; j < 2; j++) {
        int rt = (w & 1) * 2 + j;
        f16x8 bf = *(const f16x8*)&VM[(rt * 16 + l15) * 264 + kc * 32 + q * 8];
        oacc[j] = MFMA(af, bf, oacc[j]);
      }
    }
    #pragma unroll
    for (int j = 0; j < 2; j++) {
      int rt = (w & 1) * 2 + j;
      #pragma unroll
      for (int reg = 0; reg < 4; reg++) {
        int row = nt * 16 + q * 4 + reg;
        OT[row * 72 + rt * 16 + l15] = (f16)(oacc[j][reg] / denomS[row]);
      }
    }
  }
  __syncthreads();

  // M'[n][s] = silu( sum_r OT[n][r] Wo[s][r] ) -> Mst (QT reused, stride 64)
  f16* Mst = QT;
  {
    int nt = w >> 1;
    f16x8 a0 = *(const f16x8*)&OT[(nt * 16 + l15) * 72 + q * 8];
    f16x8 a1 = *(const f16x8*)&OT[(nt * 16 + l15) * 72 + 32 + q * 8];
    #pragma unroll
    for (int j = 0; j < 2; j++) {
      int st = (w & 1) * 2 + j;
      f16x8 b0 = *(const f16x8*)(Wo + (st * 16 + l15) * 64 + q * 8);
      f16x8 b1 = *(const f16x8*)(Wo + (st * 16 + l15) * 64 + 32 + q * 8);
      f32x4 acc = {}; acc = MFMA(a0, b0, acc); acc = MFMA(a1, b1, acc);
      #pragma unroll
      for (int reg = 0; reg < 4; reg++) {
        float z = acc[reg];
        Mst[(nt * 16 + q * 4 + reg) * 64 + st * 16 + l15] = (f16)(z * sigmoidf_(z));
      }
    }
  }
  __syncthreads();

  if (LAYER < 2) {
    int row = t >> 3, c = t & 7;
    *(uint4*)(Mout + (size_t)b * 16384 + (size_t)(n0 + row) * 64 + c * 8)
        = *(const uint4*)&Mst[row * 64 + c * 8];
  } else {
    float contrib = 0.0f;
    if (t < 64) {
      int ntok = n0 + t;
      const f16* row = &Mst[t * 64];
      float d[4] = {0, 0, 0, 0}, pp = 0.0f;
      #pragma unroll
      for (int gg = 0; gg < 8; gg++) {
        f16x8 v = *(const f16x8*)(row + gg * 8);
        float ss = 0.0f;
        #pragma unroll
        for (int k = 0; k < 8; k++) { float f = (float)v[k]; ss += f * f; }
        if (gg < 4) d[gg] = ss; else pp += ss;
      }
      int np = ntok >> 1, c0 = (ntok & 1) * 2;
      const float* xb = x + (size_t)b * 524288 + (size_t)c0 * 256;
      float q1a = xb[np], q1b = xb[256 + np];
      float q2a = xb[128 + np], q2b = xb[384 + np];
      contrib = d[0] * (q1a * q1a + q1b * q1b)
              + (d[1] + d[2]) * (q1a * q2a + q1b * q2b)
              + d[3] * (q2a * q2a + q2b * q2b) + pp;
    }
    if (w == 0) {
      #pragma unroll
      for (int off = 32; off; off >>= 1) contrib += __shfl_down(contrib, off);
      if (lane == 0) atomicAdd(out + b, contrib);
    }
  }
}

// ---------------------------------------------------------------------------
extern "C" void kernel_launch(void* const* d_in, const int* in_sizes, int n_in,
                              void* d_out, int out_size, void* d_ws, size_t ws_size,
                              hipStream_t stream) {
  const float* x   = (const float*)d_in[0];
  const float* L   = (const float*)d_in[1];
  const float* Aq  = (const float*)d_in[2];
  const float* Ak  = (const float*)d_in[3];
  const float* Av  = (const float*)d_in[4];
  const float* Aq1 = (const float*)d_in[5];
  const float* Ak1 = (const float*)d_in[6];
  const float* Av1 = (const float*)d_in[7];
  const float* Aq5 = (const float*)d_in[8];
  const float* Ak5 = (const float*)d_in[9];
  const float* Av5 = (const float*)d_in[10];
  const float* Ao  = (const float*)d_in[11];
  const float* Ao1 = (const float*)d_in[12];
  const float* Ao5 = (const float*)d_in[13];

  char* ws = (char*)d_ws;
  float* scale = (float*)ws;                      // 256 B
  f16* Wopt = (f16*)(ws + 256);                   // 786432 B
  f16* Wsm  = (f16*)(ws + 786688);                // 73728 B
  f16* xTg  = (f16*)(ws + 860416);                // 64 MB
  f16* Qtg  = (f16*)(ws + 860416 + 67108864);     // 2 MB
  f16* Ktg  = (f16*)(ws + 860416 + 69206016);     // 2 MB
  f16* Vgg  = (f16*)(ws + 860416 + 71303168);     // 2 MB
  f16* Mbuf = (f16*)(ws + 860416 + 73400320);     // 2 MB
  float* out = (float*)d_out;

  prep_kernel<<<170, 256, 0, stream>>>(L, Aq, Ak, Av, Aq1, Ak1, Av1,
                                       Aq5, Ak5, Av5, Ao, Ao1, Ao5,
                                       scale, Wopt, Wsm, out);
  xt_kernel<<<dim3(32, 64), 256, 0, stream>>>(x, xTg);
  qkv_kernel<<<dim3(8, 64), 256, 0, stream>>>(xTg, Wopt, Qtg, Ktg, Vgg);
  attn_kernel<0><<<dim3(4, 64), 512, 0, stream>>>(x, scale, Wsm, Qtg, Ktg, Vgg, Mbuf, out);
  proj_kernel<1><<<dim3(4, 64), 256, 0, stream>>>(Mbuf, Wsm, Qtg, Ktg, Vgg);
  attn_kernel<1><<<dim3(4, 64), 512, 0, stream>>>(x, scale, Wsm, Qtg, Ktg, Vgg, Mbuf, out);
  proj_kernel<2><<<dim3(4, 64), 256, 0, stream>>>(Mbuf, Wsm, Qtg, Ktg, Vgg);
  attn_kernel<2><<<dim3(4, 64), 512, 0, stream>>>(x, scale, Wsm, Qtg, Ktg, Vgg, nullptr, out);
}